// Round 1
// 976.758 us; speedup vs baseline: 1.4311x; 1.4311x over previous
//
#include <hip/hip_runtime.h>
#include <hip/hip_bf16.h>

#define A_N 21
#define D_N 128
#define H_N 256
#define V_N 32000
#define N_TOK 4096
#define EPS 1e-5f

typedef short bf16x8 __attribute__((ext_vector_type(8)));
typedef float floatx4 __attribute__((ext_vector_type(4)));

__device__ inline short f2bf(float f) {
    unsigned u = __builtin_bit_cast(unsigned, f);
    unsigned r = u + 0x7fffu + ((u >> 16) & 1u);
    return (short)(r >> 16);
}
__device__ inline float bf2f(short h) {
    unsigned u = ((unsigned)(unsigned short)h) << 16;
    return __builtin_bit_cast(float, u);
}

// ---------------------------------------------------------------------------
// Kernel 1: transpose + bf16-convert Wout [128][32000] -> WoutT [32000][128]
// ---------------------------------------------------------------------------
__global__ __launch_bounds__(256) void transpose_wout(
    const float* __restrict__ Wout, short* __restrict__ WoutT)
{
    __shared__ float tile[32][33];
    int n0 = blockIdx.x * 32;   // 1000 blocks in x
    int d0 = blockIdx.y * 32;   // 4 blocks in y
    int c = threadIdx.x & 31;
    int r = threadIdx.x >> 5;   // 0..7
#pragma unroll
    for (int rr = 0; rr < 4; ++rr) {
        int d = d0 + r + rr * 8;
        tile[r + rr * 8][c] = Wout[(long)d * V_N + n0 + c];
    }
    __syncthreads();
#pragma unroll
    for (int rr = 0; rr < 4; ++rr) {
        int n = n0 + r + rr * 8;
        WoutT[(long)n * 128 + d0 + c] = f2bf(tile[c][r + rr * 8]);
    }
}

// ---------------------------------------------------------------------------
// Kernel 1b: transpose W1 [a][128][256] -> W1T [a][256][128] hi/lo bf16
//            and      W2 [a][256][128] -> W2T [a][128][256] hi/lo bf16
// grid (8,8,42): z<21 -> W1 agent z ; z>=21 -> W2 agent z-21
// ---------------------------------------------------------------------------
__global__ __launch_bounds__(256) void prep_w(
    const float* __restrict__ W1, const float* __restrict__ W2,
    short* __restrict__ W1Thi, short* __restrict__ W1Tlo,
    short* __restrict__ W2Thi, short* __restrict__ W2Tlo)
{
    __shared__ float tile[32][33];
    int z = blockIdx.z;
    int which = (z >= A_N) ? 1 : 0;
    int a = which ? (z - A_N) : z;
    int R = which ? 256 : 128;   // src rows
    int C = which ? 128 : 256;   // src cols
    if ((int)blockIdx.x * 32 >= C || (int)blockIdx.y * 32 >= R) return;
    const float* src = (which ? W2 : W1) + (long)a * 32768;
    short* dsth = (which ? W2Thi : W1Thi) + (long)a * 32768;
    short* dstl = (which ? W2Tlo : W1Tlo) + (long)a * 32768;
    int c = threadIdx.x & 31, r = threadIdx.x >> 5;
    int c0 = blockIdx.x * 32, r0 = blockIdx.y * 32;
#pragma unroll
    for (int rr = 0; rr < 4; ++rr)
        tile[r + rr * 8][c] = src[(long)(r0 + r + rr * 8) * C + c0 + c];
    __syncthreads();
#pragma unroll
    for (int rr = 0; rr < 4; ++rr) {
        float v = tile[c][r + rr * 8];
        int orow = c0 + r + rr * 8;          // out row = src col
        short h = f2bf(v);
        dsth[(long)orow * R + r0 + c] = h;
        dstl[(long)orow * R + r0 + c] = f2bf(v - bf2f(h));
    }
}

// ---------------------------------------------------------------------------
// Kernel 1c: LN1 -> xhat fp32 [4096][128]; also zero accum [4096][128]
// grid 64, block 256: thread = (token = tid>>2, quarter q = tid&3)
// ---------------------------------------------------------------------------
__global__ __launch_bounds__(256) void ln1_prep(
    const int* __restrict__ x, const float* __restrict__ emb,
    float* __restrict__ xhatF, float* __restrict__ accum)
{
    int tid = threadIdx.x;
    int tok = blockIdx.x * 64 + (tid >> 2);
    int q = tid & 3;
    const float* ep = emb + (long)x[tok] * 128 + q * 32;
    float4 v[8];
    float s = 0.f, s2 = 0.f;
#pragma unroll
    for (int i = 0; i < 8; ++i) {
        v[i] = *(const float4*)(ep + i * 4);
        s  += v[i].x + v[i].y + v[i].z + v[i].w;
        s2 += v[i].x * v[i].x + v[i].y * v[i].y + v[i].z * v[i].z + v[i].w * v[i].w;
    }
    s  += __shfl_xor(s, 1);  s2 += __shfl_xor(s2, 1);
    s  += __shfl_xor(s, 2);  s2 += __shfl_xor(s2, 2);
    float mu = s * (1.f / 128.f);
    float var = s2 * (1.f / 128.f) - mu * mu;
    float rs = rsqrtf(var + EPS);
    float* xp = xhatF + (long)tok * 128 + q * 32;
#pragma unroll
    for (int i = 0; i < 8; ++i) {
        float4 o;
        o.x = (v[i].x - mu) * rs; o.y = (v[i].y - mu) * rs;
        o.z = (v[i].z - mu) * rs; o.w = (v[i].w - mu) * rs;
        *(float4*)(xp + i * 4) = o;
    }
    float4* az = (float4*)(accum + (long)blockIdx.x * 8192 + tid * 32);
    float4 zz = {0.f, 0.f, 0.f, 0.f};
#pragma unroll
    for (int i = 0; i < 8; ++i) az[i] = zz;
}

// ---------------------------------------------------------------------------
// Kernel 2: per-agent MLP via split-bf16 MFMA (hi+lo, 3 mfma per product).
// grid (64 token-tiles, 21 agents), 256 threads = 4 waves x 16 tokens each.
// Waves are fully independent (per-wave LDS quadrant, no cross-wave data).
// Accumulates (W2@hn + bfc2) into accum[4096][128] via fp32 atomics.
// ---------------------------------------------------------------------------
__global__ __launch_bounds__(256) void stage1_mfma(
    const float* __restrict__ xhatF,
    const float* __restrict__ g1, const float* __restrict__ b1ln,
    const short* __restrict__ W1Thi, const short* __restrict__ W1Tlo,
    const float* __restrict__ bfc1,
    const float* __restrict__ g2, const float* __restrict__ b2ln,
    const short* __restrict__ W2Thi, const short* __restrict__ W2Tlo,
    const float* __restrict__ bfc2, float* __restrict__ accum)
{
    __shared__ __attribute__((aligned(16))) float hnF[4][4096]; // 64 KB, per-wave [16][256] swizzled
    int a  = blockIdx.y;
    int T0 = blockIdx.x * 64;
    int w  = threadIdx.x >> 6;
    int l  = threadIdx.x & 63;
    int lr = l & 15;
    int lk = (l >> 4) * 8;
    int tok0 = T0 + w * 16;

    // ---- build fc1 A-fragments (xn = xhat*g1+b1, split hi/lo), kk = 0..3
    bf16x8 ahi[4], alo[4];
#pragma unroll
    for (int kk = 0; kk < 4; ++kk) {
        int d0 = kk * 32 + lk;
        const float* xp = xhatF + (long)(tok0 + lr) * 128 + d0;
        float4 xa = *(const float4*)xp, xb = *(const float4*)(xp + 4);
        const float* gp = g1 + a * 128 + d0;
        float4 ga = *(const float4*)gp, gb = *(const float4*)(gp + 4);
        const float* bp = b1ln + a * 128 + d0;
        float4 ba = *(const float4*)bp, bb = *(const float4*)(bp + 4);
        float xv[8] = {xa.x, xa.y, xa.z, xa.w, xb.x, xb.y, xb.z, xb.w};
        float gv[8] = {ga.x, ga.y, ga.z, ga.w, gb.x, gb.y, gb.z, gb.w};
        float bv[8] = {ba.x, ba.y, ba.z, ba.w, bb.x, bb.y, bb.z, bb.w};
#pragma unroll
        for (int j = 0; j < 8; ++j) {
            float v = fmaf(xv[j], gv[j], bv[j]);
            short h = f2bf(v);
            ahi[kk][j] = h;
            alo[kk][j] = f2bf(v - bf2f(h));
        }
    }

    // ---- fc1: [16 tok x 128] @ [128 x 256] -> acc1[16] (16x16 tiles over H)
    floatx4 acc1[16];
#pragma unroll
    for (int nt = 0; nt < 16; ++nt) acc1[nt] = (floatx4){0.f, 0.f, 0.f, 0.f};
    const short* W1h = W1Thi + ((long)a * 256 + lr) * 128 + lk;
    const short* W1l = W1Tlo + ((long)a * 256 + lr) * 128 + lk;
#pragma unroll
    for (int nt = 0; nt < 16; ++nt) {
        const short* bh = W1h + nt * 16 * 128;
        const short* bl = W1l + nt * 16 * 128;
        bf16x8 bhv[4], blv[4];
#pragma unroll
        for (int kk = 0; kk < 4; ++kk) {
            bhv[kk] = *(const bf16x8*)(bh + kk * 32);
            blv[kk] = *(const bf16x8*)(bl + kk * 32);
        }
#pragma unroll
        for (int kk = 0; kk < 4; ++kk) {
            acc1[nt] = __builtin_amdgcn_mfma_f32_16x16x32_bf16(ahi[kk], bhv[kk], acc1[nt], 0, 0, 0);
            acc1[nt] = __builtin_amdgcn_mfma_f32_16x16x32_bf16(alo[kk], bhv[kk], acc1[nt], 0, 0, 0);
            acc1[nt] = __builtin_amdgcn_mfma_f32_16x16x32_bf16(ahi[kk], blv[kk], acc1[nt], 0, 0, 0);
        }
    }

    // ---- bias + exact GELU + LN2 partial sums (in C-layout: token=(l>>4)*4+r, col=nt*16+lr)
    float s[4] = {0.f, 0.f, 0.f, 0.f}, s2[4] = {0.f, 0.f, 0.f, 0.f};
#pragma unroll
    for (int nt = 0; nt < 16; ++nt) {
        float bias = bfc1[a * 256 + nt * 16 + lr];
#pragma unroll
        for (int r = 0; r < 4; ++r) {
            float hv = acc1[nt][r] + bias;
            hv = 0.5f * hv * (1.f + erff(hv * 0.70710678118654752f));
            acc1[nt][r] = hv;
            s[r] += hv; s2[r] += hv * hv;
        }
    }
#pragma unroll
    for (int m = 1; m < 16; m <<= 1) {
#pragma unroll
        for (int r = 0; r < 4; ++r) {
            s[r]  += __shfl_xor(s[r], m);
            s2[r] += __shfl_xor(s2[r], m);
        }
    }
    float mu[4], rs[4];
#pragma unroll
    for (int r = 0; r < 4; ++r) {
        mu[r] = s[r] * (1.f / 256.f);
        float var = s2[r] * (1.f / 256.f) - mu[r] * mu[r];
        rs[r] = rsqrtf(var + EPS);
    }

    // ---- hn -> per-wave LDS [16][256], XOR-swizzled (col ^ ((row&7)<<2))
    float* hw = &hnF[w][0];
#pragma unroll
    for (int nt = 0; nt < 16; ++nt) {
        float g2v = g2[a * 256 + nt * 16 + lr];
        float b2v = b2ln[a * 256 + nt * 16 + lr];
#pragma unroll
        for (int r = 0; r < 4; ++r) {
            int tr = (l >> 4) * 4 + r;
            int col = nt * 16 + lr;
            hw[tr * 256 + (col ^ ((tr & 7) << 2))] =
                (acc1[nt][r] - mu[r]) * rs[r] * g2v + b2v;
        }
    }
    __syncthreads();

    // ---- fc2: [16 tok x 256] @ [256 x 128] -> acc2[8]
    floatx4 acc2[8];
#pragma unroll
    for (int nt2 = 0; nt2 < 8; ++nt2) acc2[nt2] = (floatx4){0.f, 0.f, 0.f, 0.f};
    const short* W2h = W2Thi + ((long)a * 128 + lr) * 256 + lk;
    const short* W2l = W2Tlo + ((long)a * 128 + lr) * 256 + lk;
    int xorv = (lr & 7) << 2;
    for (int kk2 = 0; kk2 < 8; ++kk2) {
        int c0 = kk2 * 32 + lk;
        float4 va = *(const float4*)&hw[lr * 256 + ((c0)     ^ xorv)];
        float4 vb = *(const float4*)&hw[lr * 256 + ((c0 + 4) ^ xorv)];
        float av[8] = {va.x, va.y, va.z, va.w, vb.x, vb.y, vb.z, vb.w};
        bf16x8 ah, al;
#pragma unroll
        for (int j = 0; j < 8; ++j) {
            short h = f2bf(av[j]);
            ah[j] = h;
            al[j] = f2bf(av[j] - bf2f(h));
        }
#pragma unroll
        for (int nt2 = 0; nt2 < 8; ++nt2) {
            bf16x8 bh = *(const bf16x8*)(W2h + nt2 * 16 * 256 + kk2 * 32);
            bf16x8 bl = *(const bf16x8*)(W2l + nt2 * 16 * 256 + kk2 * 32);
            acc2[nt2] = __builtin_amdgcn_mfma_f32_16x16x32_bf16(ah, bh, acc2[nt2], 0, 0, 0);
            acc2[nt2] = __builtin_amdgcn_mfma_f32_16x16x32_bf16(al, bh, acc2[nt2], 0, 0, 0);
            acc2[nt2] = __builtin_amdgcn_mfma_f32_16x16x32_bf16(ah, bl, acc2[nt2], 0, 0, 0);
        }
    }

    // ---- epilogue: accum += W2@hn + bfc2  (fp32 atomics, 32/thread)
#pragma unroll
    for (int nt2 = 0; nt2 < 8; ++nt2) {
        float bc = bfc2[a * 128 + nt2 * 16 + lr];
#pragma unroll
        for (int r = 0; r < 4; ++r) {
            int tr = (l >> 4) * 4 + r;
            atomicAdd(&accum[(long)(tok0 + tr) * 128 + nt2 * 16 + lr],
                      acc2[nt2][r] + bc);
        }
    }
}

// ---------------------------------------------------------------------------
// Kernel 2b: hidden = 2*flat + accum/21 -> bf16
// ---------------------------------------------------------------------------
__global__ __launch_bounds__(256) void finalize(
    const int* __restrict__ x, const float* __restrict__ emb,
    const float* __restrict__ accum, short* __restrict__ hiddenBf)
{
    int tid = threadIdx.x;
    int tok = blockIdx.x * 64 + (tid >> 2);
    int q = tid & 3;
    const float* ep = emb + (long)x[tok] * 128 + q * 32;
    const float* ap = accum + (long)tok * 128 + q * 32;
    short* hp = hiddenBf + (long)tok * 128 + q * 32;
#pragma unroll
    for (int p = 0; p < 4; ++p) {
        float4 e0 = *(const float4*)(ep + p * 8), e1 = *(const float4*)(ep + p * 8 + 4);
        float4 a0 = *(const float4*)(ap + p * 8), a1 = *(const float4*)(ap + p * 8 + 4);
        float ev[8] = {e0.x, e0.y, e0.z, e0.w, e1.x, e1.y, e1.z, e1.w};
        float av[8] = {a0.x, a0.y, a0.z, a0.w, a1.x, a1.y, a1.z, a1.w};
        bf16x8 o;
#pragma unroll
        for (int j = 0; j < 8; ++j)
            o[j] = f2bf(2.f * ev[j] + av[j] * (1.f / 21.f));
        *(bf16x8*)(hp + p * 8) = o;
    }
}

// ---------------------------------------------------------------------------
// Kernel 3: logits = hidden @ WoutT^T + bout via bf16 MFMA.
// Operands SWAPPED vs v0: mfma(B,A) puts 4 consecutive COLUMNS per lane ->
// float4 stores (16 dwordx4/thread instead of 64 dword/thread).
// ---------------------------------------------------------------------------
__global__ __launch_bounds__(256) void stage2(
    const short* __restrict__ Abf,   // hidden bf16 [4096][128]
    const short* __restrict__ Bbf,   // WoutT bf16 [32000][128]
    const float* __restrict__ bout,
    float* __restrict__ out)         // [4096][32000]
{
    int wid = threadIdx.x >> 6;
    int lane = threadIdx.x & 63;
    int m0 = blockIdx.y * 64;                 // grid.y = 64
    int n0 = blockIdx.x * 256 + wid * 64;     // grid.x = 125
    int lr = lane & 15;
    int lk = (lane >> 4) * 8;

    floatx4 acc[4][4] = {};                   // [nt(col tile)][mt(row tile)]
    const short* Ap = Abf + (long)(m0 + lr) * 128 + lk;
    const short* Bp = Bbf + (long)(n0 + lr) * 128 + lk;

#pragma unroll
    for (int kk = 0; kk < 4; ++kk) {
        bf16x8 afr[4], bfr[4];
#pragma unroll
        for (int t = 0; t < 4; ++t) {
            afr[t] = *(const bf16x8*)(Ap + t * 16 * 128 + kk * 32);
            bfr[t] = *(const bf16x8*)(Bp + t * 16 * 128 + kk * 32);
        }
#pragma unroll
        for (int nt = 0; nt < 4; ++nt)
#pragma unroll
            for (int mt = 0; mt < 4; ++mt)
                acc[nt][mt] = __builtin_amdgcn_mfma_f32_16x16x32_bf16(
                    bfr[nt], afr[mt], acc[nt][mt], 0, 0, 0);
    }

    // C-layout after swap: token = m0+mt*16+(lane&15); cols = n0+nt*16+(lane>>4)*4+r
    int colq = (lane >> 4) * 4;
#pragma unroll
    for (int nt = 0; nt < 4; ++nt) {
        int colb = n0 + nt * 16 + colq;
        float4 bo = *(const float4*)(bout + colb);
#pragma unroll
        for (int mt = 0; mt < 4; ++mt) {
            int tok = m0 + mt * 16 + lr;
            float4 o;
            o.x = acc[nt][mt][0] + bo.x;
            o.y = acc[nt][mt][1] + bo.y;
            o.z = acc[nt][mt][2] + bo.z;
            o.w = acc[nt][mt][3] + bo.w;
            *(float4*)(out + (long)tok * V_N + colb) = o;
        }
    }
}

// ---------------------------------------------------------------------------
extern "C" void kernel_launch(void* const* d_in, const int* in_sizes, int n_in,
                              void* d_out, int out_size, void* d_ws, size_t ws_size,
                              hipStream_t stream) {
    const int*   x    = (const int*)d_in[0];
    const float* emb  = (const float*)d_in[1];
    const float* Wout = (const float*)d_in[2];
    const float* bout = (const float*)d_in[3];
    const float* g1   = (const float*)d_in[4];
    const float* b1   = (const float*)d_in[5];
    const float* W1   = (const float*)d_in[6];
    const float* bfc1 = (const float*)d_in[7];
    const float* g2   = (const float*)d_in[8];
    const float* b2   = (const float*)d_in[9];
    const float* W2   = (const float*)d_in[10];
    const float* bfc2 = (const float*)d_in[11];
    float* out = (float*)d_out;

    char* ws = (char*)d_ws;
    short* WoutT    = (short*)ws;                    // 8,192,000 B
    short* hiddenBf = (short*)(ws + 8192000);        // 1,048,576 B
    float* xhatF    = (float*)(ws + 9240576);        // 2,097,152 B
    float* accum    = (float*)(ws + 11337728);       // 2,097,152 B
    short* W1Thi    = (short*)(ws + 13434880);       // 1,376,256 B
    short* W1Tlo    = (short*)(ws + 14811136);       // 1,376,256 B
    short* W2Thi    = (short*)(ws + 16187392);       // 1,376,256 B
    short* W2Tlo    = (short*)(ws + 17563648);       // 1,376,256 B  (end ~18.9 MB)

    transpose_wout<<<dim3(1000, 4), dim3(256), 0, stream>>>(Wout, WoutT);
    prep_w<<<dim3(8, 8, 42), dim3(256), 0, stream>>>(W1, W2, W1Thi, W1Tlo, W2Thi, W2Tlo);
    ln1_prep<<<dim3(64), dim3(256), 0, stream>>>(x, emb, xhatF, accum);
    stage1_mfma<<<dim3(64, 21), dim3(256), 0, stream>>>(xhatF, g1, b1,
        W1Thi, W1Tlo, bfc1, g2, b2, W2Thi, W2Tlo, bfc2, accum);
    finalize<<<dim3(64), dim3(256), 0, stream>>>(x, emb, accum, hiddenBf);
    stage2<<<dim3(125, 64), dim3(256), 0, stream>>>(hiddenBf, WoutT, bout, out);
}

// Round 2
// 951.624 us; speedup vs baseline: 1.4689x; 1.0264x over previous
//
#include <hip/hip_runtime.h>
#include <hip/hip_bf16.h>

#define A_N 21
#define D_N 128
#define H_N 256
#define V_N 32000
#define N_TOK 4096
#define EPS 1e-5f

typedef short bf16x8 __attribute__((ext_vector_type(8)));
typedef float floatx4 __attribute__((ext_vector_type(4)));

__device__ inline short f2bf(float f) {
    unsigned u = __builtin_bit_cast(unsigned, f);
    unsigned r = u + 0x7fffu + ((u >> 16) & 1u);
    return (short)(r >> 16);
}
__device__ inline float bf2f(short h) {
    unsigned u = ((unsigned)(unsigned short)h) << 16;
    return __builtin_bit_cast(float, u);
}

// ---------------------------------------------------------------------------
// Kernel 1: transpose + bf16-convert Wout [128][32000] -> WoutT [32000][128]
// ---------------------------------------------------------------------------
__global__ __launch_bounds__(256) void transpose_wout(
    const float* __restrict__ Wout, short* __restrict__ WoutT)
{
    __shared__ float tile[32][33];
    int n0 = blockIdx.x * 32;
    int d0 = blockIdx.y * 32;
    int c = threadIdx.x & 31;
    int r = threadIdx.x >> 5;
#pragma unroll
    for (int rr = 0; rr < 4; ++rr) {
        int d = d0 + r + rr * 8;
        tile[r + rr * 8][c] = Wout[(long)d * V_N + n0 + c];
    }
    __syncthreads();
#pragma unroll
    for (int rr = 0; rr < 4; ++rr) {
        int n = n0 + r + rr * 8;
        WoutT[(long)n * 128 + d0 + c] = f2bf(tile[c][r + rr * 8]);
    }
}

// ---------------------------------------------------------------------------
// Kernel 1b: W1 [a][128][256] -> W1T [a][256][128] hi/lo bf16
//            W2 [a][256][128] -> W2T [a][128][256] hi/lo bf16
// ---------------------------------------------------------------------------
__global__ __launch_bounds__(256) void prep_w(
    const float* __restrict__ W1, const float* __restrict__ W2,
    short* __restrict__ W1Thi, short* __restrict__ W1Tlo,
    short* __restrict__ W2Thi, short* __restrict__ W2Tlo)
{
    __shared__ float tile[32][33];
    int z = blockIdx.z;
    int which = (z >= A_N) ? 1 : 0;
    int a = which ? (z - A_N) : z;
    int R = which ? 256 : 128;
    int C = which ? 128 : 256;
    if ((int)blockIdx.x * 32 >= C || (int)blockIdx.y * 32 >= R) return;
    const float* src = (which ? W2 : W1) + (long)a * 32768;
    short* dsth = (which ? W2Thi : W1Thi) + (long)a * 32768;
    short* dstl = (which ? W2Tlo : W1Tlo) + (long)a * 32768;
    int c = threadIdx.x & 31, r = threadIdx.x >> 5;
    int c0 = blockIdx.x * 32, r0 = blockIdx.y * 32;
#pragma unroll
    for (int rr = 0; rr < 4; ++rr)
        tile[r + rr * 8][c] = src[(long)(r0 + r + rr * 8) * C + c0 + c];
    __syncthreads();
#pragma unroll
    for (int rr = 0; rr < 4; ++rr) {
        float v = tile[c][r + rr * 8];
        int orow = c0 + r + rr * 8;
        short h = f2bf(v);
        dsth[(long)orow * R + r0 + c] = h;
        dstl[(long)orow * R + r0 + c] = f2bf(v - bf2f(h));
    }
}

// ---------------------------------------------------------------------------
// Kernel 1c: LN1 -> xhat fp32 [4096][128]
// ---------------------------------------------------------------------------
__global__ __launch_bounds__(256) void ln1_prep(
    const int* __restrict__ x, const float* __restrict__ emb,
    float* __restrict__ xhatF)
{
    int tid = threadIdx.x;
    int tok = blockIdx.x * 64 + (tid >> 2);
    int q = tid & 3;
    const float* ep = emb + (long)x[tok] * 128 + q * 32;
    float4 v[8];
    float s = 0.f, s2 = 0.f;
#pragma unroll
    for (int i = 0; i < 8; ++i) {
        v[i] = *(const float4*)(ep + i * 4);
        s  += v[i].x + v[i].y + v[i].z + v[i].w;
        s2 += v[i].x * v[i].x + v[i].y * v[i].y + v[i].z * v[i].z + v[i].w * v[i].w;
    }
    s  += __shfl_xor(s, 1);  s2 += __shfl_xor(s2, 1);
    s  += __shfl_xor(s, 2);  s2 += __shfl_xor(s2, 2);
    float mu = s * (1.f / 128.f);
    float var = s2 * (1.f / 128.f) - mu * mu;
    float rs = rsqrtf(var + EPS);
    float* xp = xhatF + (long)tok * 128 + q * 32;
#pragma unroll
    for (int i = 0; i < 8; ++i) {
        float4 o;
        o.x = (v[i].x - mu) * rs; o.y = (v[i].y - mu) * rs;
        o.z = (v[i].z - mu) * rs; o.w = (v[i].w - mu) * rs;
        *(float4*)(xp + i * 4) = o;
    }
}

// ---------------------------------------------------------------------------
// Kernel 2: agent-group MLP. grid (64 token-tiles, 7 groups); each of 4
// independent waves owns 16 tokens and loops 3 agents, accumulating the
// fc2 output in registers (MFMA C-in). NO atomics, NO barriers.
// ---------------------------------------------------------------------------
__global__ __launch_bounds__(256) void stage1_mfma(
    const float* __restrict__ xhatF,
    const float* __restrict__ g1, const float* __restrict__ b1ln,
    const short* __restrict__ W1Thi, const short* __restrict__ W1Tlo,
    const float* __restrict__ bfc1,
    const float* __restrict__ g2, const float* __restrict__ b2ln,
    const short* __restrict__ W2Thi, const short* __restrict__ W2Tlo,
    const float* __restrict__ bfc2, float* __restrict__ partials)
{
    __shared__ __attribute__((aligned(16))) float hnF[4][4096]; // per-wave [16][256] swizzled
    int g  = blockIdx.y;
    int T0 = blockIdx.x * 64;
    int w  = threadIdx.x >> 6;
    int l  = threadIdx.x & 63;
    int lr = l & 15;
    int lk = (l >> 4) * 8;
    int tok0 = T0 + w * 16;
    float* hw = &hnF[w][0];
    int xorv = (lr & 7) << 2;

    // cache this wave's xhat rows once (reused by all 3 agents)
    float xq[4][8];
#pragma unroll
    for (int kk = 0; kk < 4; ++kk) {
        const float* xp = xhatF + (long)(tok0 + lr) * 128 + kk * 32 + lk;
        float4 xa = *(const float4*)xp, xb = *(const float4*)(xp + 4);
        xq[kk][0] = xa.x; xq[kk][1] = xa.y; xq[kk][2] = xa.z; xq[kk][3] = xa.w;
        xq[kk][4] = xb.x; xq[kk][5] = xb.y; xq[kk][6] = xb.z; xq[kk][7] = xb.w;
    }

    floatx4 accO[8];   // fc2 accumulator, carried across agents
#pragma unroll
    for (int nt2 = 0; nt2 < 8; ++nt2) accO[nt2] = (floatx4){0.f, 0.f, 0.f, 0.f};

#pragma unroll 1
    for (int ai = 0; ai < 3; ++ai) {
        int a = g * 3 + ai;

        // ---- fc1 A-fragments: xn = xhat*g1 + b1, split hi/lo
        bf16x8 ahi[4], alo[4];
#pragma unroll
        for (int kk = 0; kk < 4; ++kk) {
            const float* gp = g1 + a * 128 + kk * 32 + lk;
            const float* bp = b1ln + a * 128 + kk * 32 + lk;
            float4 ga = *(const float4*)gp, gb = *(const float4*)(gp + 4);
            float4 ba = *(const float4*)bp, bb = *(const float4*)(bp + 4);
            float gv[8] = {ga.x, ga.y, ga.z, ga.w, gb.x, gb.y, gb.z, gb.w};
            float bv[8] = {ba.x, ba.y, ba.z, ba.w, bb.x, bb.y, bb.z, bb.w};
#pragma unroll
            for (int j = 0; j < 8; ++j) {
                float v = fmaf(xq[kk][j], gv[j], bv[j]);
                short h = f2bf(v);
                ahi[kk][j] = h;
                alo[kk][j] = f2bf(v - bf2f(h));
            }
        }

        // ---- fc1: kk-outer / nt-inner -> 16 independent MFMA chains
        floatx4 acc1[16];
#pragma unroll
        for (int nt = 0; nt < 16; ++nt) acc1[nt] = (floatx4){0.f, 0.f, 0.f, 0.f};
        const short* W1h = W1Thi + ((long)a * 256 + lr) * 128 + lk;
        const short* W1l = W1Tlo + ((long)a * 256 + lr) * 128 + lk;
#pragma unroll
        for (int kk = 0; kk < 4; ++kk) {
#pragma unroll
            for (int nt = 0; nt < 16; ++nt) {
                bf16x8 bh = *(const bf16x8*)(W1h + nt * 2048 + kk * 32);
                bf16x8 bl = *(const bf16x8*)(W1l + nt * 2048 + kk * 32);
                acc1[nt] = __builtin_amdgcn_mfma_f32_16x16x32_bf16(ahi[kk], bh, acc1[nt], 0, 0, 0);
                acc1[nt] = __builtin_amdgcn_mfma_f32_16x16x32_bf16(alo[kk], bh, acc1[nt], 0, 0, 0);
                acc1[nt] = __builtin_amdgcn_mfma_f32_16x16x32_bf16(ahi[kk], bl, acc1[nt], 0, 0, 0);
            }
        }

        // ---- bias + exact GELU + LN2 partial sums
        float s[4] = {0.f, 0.f, 0.f, 0.f}, s2[4] = {0.f, 0.f, 0.f, 0.f};
#pragma unroll
        for (int nt = 0; nt < 16; ++nt) {
            float bias = bfc1[a * 256 + nt * 16 + lr];
#pragma unroll
            for (int r = 0; r < 4; ++r) {
                float hv = acc1[nt][r] + bias;
                hv = 0.5f * hv * (1.f + erff(hv * 0.70710678118654752f));
                acc1[nt][r] = hv;
                s[r] += hv; s2[r] += hv * hv;
            }
        }
#pragma unroll
        for (int m = 1; m < 16; m <<= 1) {
#pragma unroll
            for (int r = 0; r < 4; ++r) {
                s[r]  += __shfl_xor(s[r], m);
                s2[r] += __shfl_xor(s2[r], m);
            }
        }
        float mu[4], rs[4];
#pragma unroll
        for (int r = 0; r < 4; ++r) {
            mu[r] = s[r] * (1.f / 256.f);
            float var = s2[r] * (1.f / 256.f) - mu[r] * mu[r];
            rs[r] = rsqrtf(var + EPS);
        }

        // ---- hn -> per-wave LDS [16][256], XOR-swizzled (col ^ ((row&7)<<2))
#pragma unroll
        for (int nt = 0; nt < 16; ++nt) {
            float g2v = g2[a * 256 + nt * 16 + lr];
            float b2v = b2ln[a * 256 + nt * 16 + lr];
#pragma unroll
            for (int r = 0; r < 4; ++r) {
                int tr = (l >> 4) * 4 + r;
                int col = nt * 16 + lr;
                hw[tr * 256 + (col ^ ((tr & 7) << 2))] =
                    (acc1[nt][r] - mu[r]) * rs[r] * g2v + b2v;
            }
        }

        // ---- fc2 (swapped operands): accO[nt2] holds C[d-tile][token]
        const short* W2h = W2Thi + ((long)a * 128 + lr) * 256 + lk;
        const short* W2l = W2Tlo + ((long)a * 128 + lr) * 256 + lk;
#pragma unroll
        for (int kk2 = 0; kk2 < 8; ++kk2) {
            int c0 = kk2 * 32 + lk;
            float4 va = *(const float4*)&hw[lr * 256 + ((c0)     ^ xorv)];
            float4 vb = *(const float4*)&hw[lr * 256 + ((c0 + 4) ^ xorv)];
            float av[8] = {va.x, va.y, va.z, va.w, vb.x, vb.y, vb.z, vb.w};
            bf16x8 ah, al;
#pragma unroll
            for (int j = 0; j < 8; ++j) {
                short h = f2bf(av[j]);
                ah[j] = h;
                al[j] = f2bf(av[j] - bf2f(h));
            }
#pragma unroll
            for (int nt2 = 0; nt2 < 8; ++nt2) {
                bf16x8 bh = *(const bf16x8*)(W2h + nt2 * 16 * 256 + kk2 * 32);
                bf16x8 bl = *(const bf16x8*)(W2l + nt2 * 16 * 256 + kk2 * 32);
                accO[nt2] = __builtin_amdgcn_mfma_f32_16x16x32_bf16(bh, ah, accO[nt2], 0, 0, 0);
                accO[nt2] = __builtin_amdgcn_mfma_f32_16x16x32_bf16(bh, al, accO[nt2], 0, 0, 0);
                accO[nt2] = __builtin_amdgcn_mfma_f32_16x16x32_bf16(bl, ah, accO[nt2], 0, 0, 0);
            }
        }
    }

    // ---- epilogue: add group's bfc2 sum, plain float4 stores (no atomics)
    int colq = (l >> 4) * 4;
    int a0 = g * 3;
    float* prow = partials + ((long)g * N_TOK + tok0 + lr) * 128;
#pragma unroll
    for (int nt2 = 0; nt2 < 8; ++nt2) {
        int d = nt2 * 16 + colq;
        float4 b0 = *(const float4*)(bfc2 + a0 * 128 + d);
        float4 b1v = *(const float4*)(bfc2 + (a0 + 1) * 128 + d);
        float4 b2v = *(const float4*)(bfc2 + (a0 + 2) * 128 + d);
        float4 o;
        o.x = accO[nt2][0] + b0.x + b1v.x + b2v.x;
        o.y = accO[nt2][1] + b0.y + b1v.y + b2v.y;
        o.z = accO[nt2][2] + b0.z + b1v.z + b2v.z;
        o.w = accO[nt2][3] + b0.w + b1v.w + b2v.w;
        *(float4*)(prow + d) = o;
    }
}

// ---------------------------------------------------------------------------
// Kernel 2b: hidden = 2*flat + (sum of 7 group partials)/21 -> bf16
// ---------------------------------------------------------------------------
__global__ __launch_bounds__(256) void finalize(
    const int* __restrict__ x, const float* __restrict__ emb,
    const float* __restrict__ partials, short* __restrict__ hiddenBf)
{
    int tid = threadIdx.x;
    int tok = blockIdx.x * 64 + (tid >> 2);
    int q = tid & 3;
    const float* pp = partials + (long)tok * 128 + q * 32;
    float4 s4[8];
#pragma unroll
    for (int j = 0; j < 8; ++j) s4[j] = *(const float4*)(pp + j * 4);
#pragma unroll 1
    for (int g = 1; g < 7; ++g) {
        const float* p2 = pp + (long)g * N_TOK * 128;
#pragma unroll
        for (int j = 0; j < 8; ++j) {
            float4 v = *(const float4*)(p2 + j * 4);
            s4[j].x += v.x; s4[j].y += v.y; s4[j].z += v.z; s4[j].w += v.w;
        }
    }
    const float* ep = emb + (long)x[tok] * 128 + q * 32;
    short* hp = hiddenBf + (long)tok * 128 + q * 32;
#pragma unroll
    for (int p = 0; p < 4; ++p) {
        float4 e0 = *(const float4*)(ep + p * 8), e1 = *(const float4*)(ep + p * 8 + 4);
        float ev[8] = {e0.x, e0.y, e0.z, e0.w, e1.x, e1.y, e1.z, e1.w};
        float av[8] = {s4[p * 2].x, s4[p * 2].y, s4[p * 2].z, s4[p * 2].w,
                       s4[p * 2 + 1].x, s4[p * 2 + 1].y, s4[p * 2 + 1].z, s4[p * 2 + 1].w};
        bf16x8 o;
#pragma unroll
        for (int j = 0; j < 8; ++j)
            o[j] = f2bf(2.f * ev[j] + av[j] * (1.f / 21.f));
        *(bf16x8*)(hp + p * 8) = o;
    }
}

// ---------------------------------------------------------------------------
// Kernel 3: logits = hidden @ WoutT^T + bout via bf16 MFMA (swapped operands).
// C-tile staged through swizzled LDS so every store is a full 1KB-contiguous
// wave write (16 complete output rows per wave).
// ---------------------------------------------------------------------------
__global__ __launch_bounds__(256) void stage2(
    const short* __restrict__ Abf,   // hidden bf16 [4096][128]
    const short* __restrict__ Bbf,   // WoutT bf16 [32000][128]
    const float* __restrict__ bout,
    float* __restrict__ out)         // [4096][32000]
{
    __shared__ __attribute__((aligned(16))) float cT[64][256];
    int wid = threadIdx.x >> 6;
    int lane = threadIdx.x & 63;
    int m0 = blockIdx.y * 64;                 // grid.y = 64
    int n0b = blockIdx.x * 256;               // grid.x = 125
    int n0 = n0b + wid * 64;
    int lr = lane & 15;
    int lk = (lane >> 4) * 8;

    floatx4 acc[4][4] = {};                   // [nt(col tile)][mt(row tile)]
    const short* Ap = Abf + (long)(m0 + lr) * 128 + lk;
    const short* Bp = Bbf + (long)(n0 + lr) * 128 + lk;

#pragma unroll
    for (int kk = 0; kk < 4; ++kk) {
        bf16x8 afr[4], bfr[4];
#pragma unroll
        for (int t = 0; t < 4; ++t) {
            afr[t] = *(const bf16x8*)(Ap + t * 16 * 128 + kk * 32);
            bfr[t] = *(const bf16x8*)(Bp + t * 16 * 128 + kk * 32);
        }
#pragma unroll
        for (int nt = 0; nt < 4; ++nt)
#pragma unroll
            for (int mt = 0; mt < 4; ++mt)
                acc[nt][mt] = __builtin_amdgcn_mfma_f32_16x16x32_bf16(
                    bfr[nt], afr[mt], acc[nt][mt], 0, 0, 0);
    }

    // C fragment -> LDS (swizzled: col ^ ((row&7)<<2), stays in wave's 64-col slab)
    int colq = (lane >> 4) * 4;
#pragma unroll
    for (int nt = 0; nt < 4; ++nt) {
#pragma unroll
        for (int mt = 0; mt < 4; ++mt) {
            int row = mt * 16 + lr;
            int col = wid * 64 + nt * 16 + colq;
            float4 o;
            o.x = acc[nt][mt][0]; o.y = acc[nt][mt][1];
            o.z = acc[nt][mt][2]; o.w = acc[nt][mt][3];
            *(float4*)&cT[row][col ^ ((row & 7) << 2)] = o;
        }
    }
    __syncthreads();

    // coalesced store: each wave writes 16 complete 1KB rows
    float4 bo = *(const float4*)(bout + n0b + lane * 4);
#pragma unroll
    for (int rr = 0; rr < 16; ++rr) {
        int row = wid * 16 + rr;
        float4 v = *(const float4*)&cT[row][(lane * 4) ^ ((row & 7) << 2)];
        float4 o;
        o.x = v.x + bo.x; o.y = v.y + bo.y; o.z = v.z + bo.z; o.w = v.w + bo.w;
        *(float4*)(out + (long)(m0 + row) * V_N + n0b + lane * 4) = o;
    }
}

// ---------------------------------------------------------------------------
extern "C" void kernel_launch(void* const* d_in, const int* in_sizes, int n_in,
                              void* d_out, int out_size, void* d_ws, size_t ws_size,
                              hipStream_t stream) {
    const int*   x    = (const int*)d_in[0];
    const float* emb  = (const float*)d_in[1];
    const float* Wout = (const float*)d_in[2];
    const float* bout = (const float*)d_in[3];
    const float* g1   = (const float*)d_in[4];
    const float* b1   = (const float*)d_in[5];
    const float* W1   = (const float*)d_in[6];
    const float* bfc1 = (const float*)d_in[7];
    const float* g2   = (const float*)d_in[8];
    const float* b2   = (const float*)d_in[9];
    const float* W2   = (const float*)d_in[10];
    const float* bfc2 = (const float*)d_in[11];
    float* out = (float*)d_out;

    char* ws = (char*)d_ws;
    short* WoutT    = (short*)ws;                    // 8,192,000
    short* hiddenBf = (short*)(ws + 8192000);        // 1,048,576
    float* xhatF    = (float*)(ws + 9240576);        // 2,097,152
    short* W1Thi    = (short*)(ws + 11337728);       // 1,376,256
    short* W1Tlo    = (short*)(ws + 12713984);       // 1,376,256
    short* W2Thi    = (short*)(ws + 14090240);       // 1,376,256
    short* W2Tlo    = (short*)(ws + 15466496);       // 1,376,256
    float* partials = (float*)(ws + 16842752);       // 14,680,064 (end ~31.5 MB)

    transpose_wout<<<dim3(1000, 4), dim3(256), 0, stream>>>(Wout, WoutT);
    prep_w<<<dim3(8, 8, 42), dim3(256), 0, stream>>>(W1, W2, W1Thi, W1Tlo, W2Thi, W2Tlo);
    ln1_prep<<<dim3(64), dim3(256), 0, stream>>>(x, emb, xhatF);
    stage1_mfma<<<dim3(64, 7), dim3(256), 0, stream>>>(xhatF, g1, b1,
        W1Thi, W1Tlo, bfc1, g2, b2, W2Thi, W2Tlo, bfc2, partials);
    finalize<<<dim3(64), dim3(256), 0, stream>>>(x, emb, partials, hiddenBf);
    stage2<<<dim3(125, 64), dim3(256), 0, stream>>>(hiddenBf, WoutT, bout, out);
}

// Round 3
// 897.518 us; speedup vs baseline: 1.5574x; 1.0603x over previous
//
#include <hip/hip_runtime.h>
#include <hip/hip_bf16.h>

#define A_N 21
#define D_N 128
#define H_N 256
#define V_N 32000
#define N_TOK 4096
#define EPS 1e-5f

typedef short bf16x8 __attribute__((ext_vector_type(8)));
typedef float floatx4 __attribute__((ext_vector_type(4)));

__device__ inline short f2bf(float f) {
    unsigned u = __builtin_bit_cast(unsigned, f);
    unsigned r = u + 0x7fffu + ((u >> 16) & 1u);
    return (short)(r >> 16);
}
__device__ inline float bf2f(short h) {
    unsigned u = ((unsigned)(unsigned short)h) << 16;
    return __builtin_bit_cast(float, u);
}

// ---------------------------------------------------------------------------
// Kernel 1: transpose + bf16-convert Wout [128][32000] -> WoutT [32000][128]
// ---------------------------------------------------------------------------
__global__ __launch_bounds__(256) void transpose_wout(
    const float* __restrict__ Wout, short* __restrict__ WoutT)
{
    __shared__ float tile[32][33];
    int n0 = blockIdx.x * 32;
    int d0 = blockIdx.y * 32;
    int c = threadIdx.x & 31;
    int r = threadIdx.x >> 5;
#pragma unroll
    for (int rr = 0; rr < 4; ++rr) {
        int d = d0 + r + rr * 8;
        tile[r + rr * 8][c] = Wout[(long)d * V_N + n0 + c];
    }
    __syncthreads();
#pragma unroll
    for (int rr = 0; rr < 4; ++rr) {
        int n = n0 + r + rr * 8;
        WoutT[(long)n * 128 + d0 + c] = f2bf(tile[c][r + rr * 8]);
    }
}

// ---------------------------------------------------------------------------
// Kernel 1b: pack W1/W2 into FRAGMENT-MAJOR hi/lo bf16.
// W1F[a][frag=kk*16+nt]: lane l, j -> W1[a][d=kk*32+(l>>4)*8+j][h=nt*16+(l&15)]
// W2F[a][frag=kk2*8+nt2]: lane l, j -> W2[a][h=kk2*32+(l>>4)*8+j][d=nt2*16+(l&15)]
// Each fragment: 512 shorts hi at +0, 512 shorts lo at +512 (2KB total).
// grid (16, 42): y<21 -> W1 agent y ; y>=21 -> W2 agent y-21
// ---------------------------------------------------------------------------
__global__ __launch_bounds__(256) void prep_w_frag(
    const float* __restrict__ W1, const float* __restrict__ W2,
    short* __restrict__ W1F, short* __restrict__ W2F)
{
    int z = blockIdx.y;
    int which = (z >= A_N) ? 1 : 0;
    int a = which ? (z - A_N) : z;
    int tid = threadIdx.x;
    int l = tid & 63;
    int frag = blockIdx.x * 4 + (tid >> 6);   // 0..63
    int lr = l & 15, lj = (l >> 4) * 8;
    bf16x8 vh, vl;
    short* dst;
    if (!which) {
        int kk = frag >> 4, nt = frag & 15;
        int hcol = nt * 16 + lr;
        const float* src = W1 + (long)a * 32768 + hcol;     // stride 256 over d
#pragma unroll
        for (int j = 0; j < 8; ++j) {
            int d = kk * 32 + lj + j;
            float v = src[(long)d * 256];
            short h = f2bf(v);
            vh[j] = h; vl[j] = f2bf(v - bf2f(h));
        }
        dst = W1F + (long)(a * 64 + frag) * 1024 + l * 8;
    } else {
        int kk2 = frag >> 3, nt2 = frag & 7;
        int d = nt2 * 16 + lr;
        const float* src = W2 + (long)a * 32768 + d;        // stride 128 over h
#pragma unroll
        for (int j = 0; j < 8; ++j) {
            int h = kk2 * 32 + lj + j;
            float v = src[(long)h * 128];
            short hh = f2bf(v);
            vh[j] = hh; vl[j] = f2bf(v - bf2f(hh));
        }
        dst = W2F + (long)(a * 64 + frag) * 1024 + l * 8;
    }
    *(bf16x8*)dst = vh;
    *(bf16x8*)(dst + 512) = vl;
}

// ---------------------------------------------------------------------------
// Kernel 1c: LN1 -> xhat fp32 [4096][128]
// ---------------------------------------------------------------------------
__global__ __launch_bounds__(256) void ln1_prep(
    const int* __restrict__ x, const float* __restrict__ emb,
    float* __restrict__ xhatF)
{
    int tid = threadIdx.x;
    int tok = blockIdx.x * 64 + (tid >> 2);
    int q = tid & 3;
    const float* ep = emb + (long)x[tok] * 128 + q * 32;
    float4 v[8];
    float s = 0.f, s2 = 0.f;
#pragma unroll
    for (int i = 0; i < 8; ++i) {
        v[i] = *(const float4*)(ep + i * 4);
        s  += v[i].x + v[i].y + v[i].z + v[i].w;
        s2 += v[i].x * v[i].x + v[i].y * v[i].y + v[i].z * v[i].z + v[i].w * v[i].w;
    }
    s  += __shfl_xor(s, 1);  s2 += __shfl_xor(s2, 1);
    s  += __shfl_xor(s, 2);  s2 += __shfl_xor(s2, 2);
    float mu = s * (1.f / 128.f);
    float var = s2 * (1.f / 128.f) - mu * mu;
    float rs = rsqrtf(var + EPS);
    float* xp = xhatF + (long)tok * 128 + q * 32;
#pragma unroll
    for (int i = 0; i < 8; ++i) {
        float4 o;
        o.x = (v[i].x - mu) * rs; o.y = (v[i].y - mu) * rs;
        o.z = (v[i].z - mu) * rs; o.w = (v[i].w - mu) * rs;
        *(float4*)(xp + i * 4) = o;
    }
}

// ---------------------------------------------------------------------------
// Kernel 2: agent-group MLP. 1792 one-wave blocks (256 token-tiles x 7 groups),
// XCD-swizzled so each XCD owns ~1 agent-group (weights L2-resident).
// Fragment-major weights: every load is one contiguous 1KB wave segment.
// Register accumulation across the group's 3 agents; no atomics, no barriers.
// ---------------------------------------------------------------------------
__global__ __launch_bounds__(64) void stage1_mfma(
    const float* __restrict__ xhatF,
    const float* __restrict__ g1, const float* __restrict__ b1ln,
    const short* __restrict__ W1F, const float* __restrict__ bfc1,
    const float* __restrict__ g2, const float* __restrict__ b2ln,
    const short* __restrict__ W2F, const float* __restrict__ bfc2,
    float* __restrict__ partials)
{
    __shared__ __attribute__((aligned(16))) float hw[4096];  // [16][256] swizzled
    int id = blockIdx.x;
    int t = (id & 7) * 224 + (id >> 3);       // XCD-major task order (bijective: 1792 = 8*224)
    int g = t >> 8;                           // agent group 0..6
    int tok0 = (t & 255) * 16;
    int l = threadIdx.x;                      // 0..63
    int lr = l & 15;
    int lk = (l >> 4) * 8;
    int xorv = (lr & 7) << 2;

    // cache the 16 xhat rows (reused by all 3 agents)
    float xq[4][8];
#pragma unroll
    for (int kk = 0; kk < 4; ++kk) {
        const float* xp = xhatF + (long)(tok0 + lr) * 128 + kk * 32 + lk;
        float4 xa = *(const float4*)xp, xb = *(const float4*)(xp + 4);
        xq[kk][0] = xa.x; xq[kk][1] = xa.y; xq[kk][2] = xa.z; xq[kk][3] = xa.w;
        xq[kk][4] = xb.x; xq[kk][5] = xb.y; xq[kk][6] = xb.z; xq[kk][7] = xb.w;
    }

    floatx4 accO[8];   // fc2 accumulator, carried across agents
#pragma unroll
    for (int nt2 = 0; nt2 < 8; ++nt2) accO[nt2] = (floatx4){0.f, 0.f, 0.f, 0.f};

#pragma unroll 1
    for (int ai = 0; ai < 3; ++ai) {
        int a = g * 3 + ai;

        // ---- fc1 A-fragments: xn = xhat*g1 + b1, split hi/lo
        bf16x8 ahi[4], alo[4];
#pragma unroll
        for (int kk = 0; kk < 4; ++kk) {
            const float* gp = g1 + a * 128 + kk * 32 + lk;
            const float* bp = b1ln + a * 128 + kk * 32 + lk;
            float4 ga = *(const float4*)gp, gb = *(const float4*)(gp + 4);
            float4 ba = *(const float4*)bp, bb = *(const float4*)(bp + 4);
            float gv[8] = {ga.x, ga.y, ga.z, ga.w, gb.x, gb.y, gb.z, gb.w};
            float bv[8] = {ba.x, ba.y, ba.z, ba.w, bb.x, bb.y, bb.z, bb.w};
#pragma unroll
            for (int j = 0; j < 8; ++j) {
                float v = fmaf(xq[kk][j], gv[j], bv[j]);
                short h = f2bf(v);
                ahi[kk][j] = h;
                alo[kk][j] = f2bf(v - bf2f(h));
            }
        }

        // ---- fc1: kk-outer / nt-inner, fragment-major weight loads
        floatx4 acc1[16];
#pragma unroll
        for (int nt = 0; nt < 16; ++nt) acc1[nt] = (floatx4){0.f, 0.f, 0.f, 0.f};
        const short* w1 = W1F + (long)a * 65536 + l * 8;
#pragma unroll
        for (int kk = 0; kk < 4; ++kk) {
#pragma unroll
            for (int nt = 0; nt < 16; ++nt) {
                const short* p = w1 + (kk * 16 + nt) * 1024;
                bf16x8 bh = *(const bf16x8*)p;
                bf16x8 bl = *(const bf16x8*)(p + 512);
                acc1[nt] = __builtin_amdgcn_mfma_f32_16x16x32_bf16(ahi[kk], bh, acc1[nt], 0, 0, 0);
                acc1[nt] = __builtin_amdgcn_mfma_f32_16x16x32_bf16(alo[kk], bh, acc1[nt], 0, 0, 0);
                acc1[nt] = __builtin_amdgcn_mfma_f32_16x16x32_bf16(ahi[kk], bl, acc1[nt], 0, 0, 0);
            }
        }

        // ---- bias + exact GELU + LN2 partial sums
        float s[4] = {0.f, 0.f, 0.f, 0.f}, s2[4] = {0.f, 0.f, 0.f, 0.f};
#pragma unroll
        for (int nt = 0; nt < 16; ++nt) {
            float bias = bfc1[a * 256 + nt * 16 + lr];
#pragma unroll
            for (int r = 0; r < 4; ++r) {
                float hv = acc1[nt][r] + bias;
                hv = 0.5f * hv * (1.f + erff(hv * 0.70710678118654752f));
                acc1[nt][r] = hv;
                s[r] += hv; s2[r] += hv * hv;
            }
        }
#pragma unroll
        for (int m = 1; m < 16; m <<= 1) {
#pragma unroll
            for (int r = 0; r < 4; ++r) {
                s[r]  += __shfl_xor(s[r], m);
                s2[r] += __shfl_xor(s2[r], m);
            }
        }
        float mu[4], rs[4];
#pragma unroll
        for (int r = 0; r < 4; ++r) {
            mu[r] = s[r] * (1.f / 256.f);
            float var = s2[r] * (1.f / 256.f) - mu[r] * mu[r];
            rs[r] = rsqrtf(var + EPS);
        }

        // ---- hn -> LDS [16][256], XOR-swizzled (col ^ ((row&7)<<2))
#pragma unroll
        for (int nt = 0; nt < 16; ++nt) {
            float g2v = g2[a * 256 + nt * 16 + lr];
            float b2v = b2ln[a * 256 + nt * 16 + lr];
#pragma unroll
            for (int r = 0; r < 4; ++r) {
                int tr = (l >> 4) * 4 + r;
                int col = nt * 16 + lr;
                hw[tr * 256 + (col ^ ((tr & 7) << 2))] =
                    (acc1[nt][r] - mu[r]) * rs[r] * g2v + b2v;
            }
        }

        // ---- fc2 (swapped operands), fragment-major weight loads
        const short* w2 = W2F + (long)a * 65536 + l * 8;
#pragma unroll
        for (int kk2 = 0; kk2 < 8; ++kk2) {
            int c0 = kk2 * 32 + lk;
            float4 va = *(const float4*)&hw[lr * 256 + ((c0)     ^ xorv)];
            float4 vb = *(const float4*)&hw[lr * 256 + ((c0 + 4) ^ xorv)];
            float av[8] = {va.x, va.y, va.z, va.w, vb.x, vb.y, vb.z, vb.w};
            bf16x8 ah, al;
#pragma unroll
            for (int j = 0; j < 8; ++j) {
                short h = f2bf(av[j]);
                ah[j] = h;
                al[j] = f2bf(av[j] - bf2f(h));
            }
#pragma unroll
            for (int nt2 = 0; nt2 < 8; ++nt2) {
                const short* p = w2 + (kk2 * 8 + nt2) * 1024;
                bf16x8 bh = *(const bf16x8*)p;
                bf16x8 bl = *(const bf16x8*)(p + 512);
                accO[nt2] = __builtin_amdgcn_mfma_f32_16x16x32_bf16(bh, ah, accO[nt2], 0, 0, 0);
                accO[nt2] = __builtin_amdgcn_mfma_f32_16x16x32_bf16(bh, al, accO[nt2], 0, 0, 0);
                accO[nt2] = __builtin_amdgcn_mfma_f32_16x16x32_bf16(bl, ah, accO[nt2], 0, 0, 0);
            }
        }
    }

    // ---- epilogue: add group's bfc2 sum, plain float4 stores
    int colq = (l >> 4) * 4;
    int a0 = g * 3;
    float* prow = partials + ((long)g * N_TOK + tok0 + lr) * 128;
#pragma unroll
    for (int nt2 = 0; nt2 < 8; ++nt2) {
        int d = nt2 * 16 + colq;
        float4 b0 = *(const float4*)(bfc2 + a0 * 128 + d);
        float4 b1v = *(const float4*)(bfc2 + (a0 + 1) * 128 + d);
        float4 b2v = *(const float4*)(bfc2 + (a0 + 2) * 128 + d);
        float4 o;
        o.x = accO[nt2][0] + b0.x + b1v.x + b2v.x;
        o.y = accO[nt2][1] + b0.y + b1v.y + b2v.y;
        o.z = accO[nt2][2] + b0.z + b1v.z + b2v.z;
        o.w = accO[nt2][3] + b0.w + b1v.w + b2v.w;
        *(float4*)(prow + d) = o;
    }
}

// ---------------------------------------------------------------------------
// Kernel 2b: hidden = 2*flat + (sum of 7 group partials)/21 -> bf16
// ---------------------------------------------------------------------------
__global__ __launch_bounds__(256) void finalize(
    const int* __restrict__ x, const float* __restrict__ emb,
    const float* __restrict__ partials, short* __restrict__ hiddenBf)
{
    int tid = threadIdx.x;
    int tok = blockIdx.x * 64 + (tid >> 2);
    int q = tid & 3;
    const float* pp = partials + (long)tok * 128 + q * 32;
    float4 s4[8];
#pragma unroll
    for (int j = 0; j < 8; ++j) s4[j] = *(const float4*)(pp + j * 4);
#pragma unroll 1
    for (int g = 1; g < 7; ++g) {
        const float* p2 = pp + (long)g * N_TOK * 128;
#pragma unroll
        for (int j = 0; j < 8; ++j) {
            float4 v = *(const float4*)(p2 + j * 4);
            s4[j].x += v.x; s4[j].y += v.y; s4[j].z += v.z; s4[j].w += v.w;
        }
    }
    const float* ep = emb + (long)x[tok] * 128 + q * 32;
    short* hp = hiddenBf + (long)tok * 128 + q * 32;
#pragma unroll
    for (int p = 0; p < 4; ++p) {
        float4 e0 = *(const float4*)(ep + p * 8), e1 = *(const float4*)(ep + p * 8 + 4);
        float ev[8] = {e0.x, e0.y, e0.z, e0.w, e1.x, e1.y, e1.z, e1.w};
        float av[8] = {s4[p * 2].x, s4[p * 2].y, s4[p * 2].z, s4[p * 2].w,
                       s4[p * 2 + 1].x, s4[p * 2 + 1].y, s4[p * 2 + 1].z, s4[p * 2 + 1].w};
        bf16x8 o;
#pragma unroll
        for (int j = 0; j < 8; ++j)
            o[j] = f2bf(2.f * ev[j] + av[j] * (1.f / 21.f));
        *(bf16x8*)(hp + p * 8) = o;
    }
}

// ---------------------------------------------------------------------------
// Kernel 3: logits = hidden @ WoutT^T + bout (swapped-operand MFMA).
// M-tile = 256: B fragments held in registers across 4 m-sub-tiles -> WoutT
// L2 re-read traffic /4. XCD-swizzled so each XCD owns a vocab stripe.
// C staged through swizzled LDS; stores are full 1KB-contiguous wave writes.
// ---------------------------------------------------------------------------
__global__ __launch_bounds__(256) void stage2(
    const short* __restrict__ Abf,   // hidden bf16 [4096][128]
    const short* __restrict__ Bbf,   // WoutT bf16 [32000][128]
    const float* __restrict__ bout,
    float* __restrict__ out)         // [4096][32000]
{
    __shared__ __attribute__((aligned(16))) float cT[64][256];
    int id = blockIdx.x;                       // 0..1999 flat (2000 = 8*250)
    int tt = (id & 7) * 250 + (id >> 3);       // bijective XCD-major
    int nb = tt >> 4;                          // vocab block 0..124
    int mb = tt & 15;                          // 256-token super-block 0..15
    int wid = threadIdx.x >> 6;
    int lane = threadIdx.x & 63;
    int m0 = mb * 256;
    int n0b = nb * 256;
    int n0 = n0b + wid * 64;
    int lr = lane & 15;
    int lk = (lane >> 4) * 8;

    // B fragments once per block
    bf16x8 bfr[4][4];                          // [kk][nt]
    const short* Bp = Bbf + (long)(n0 + lr) * 128 + lk;
#pragma unroll
    for (int kk = 0; kk < 4; ++kk)
#pragma unroll
        for (int nt = 0; nt < 4; ++nt)
            bfr[kk][nt] = *(const bf16x8*)(Bp + nt * 16 * 128 + kk * 32);

    float4 bo = *(const float4*)(bout + n0b + lane * 4);
    int colq = (lane >> 4) * 4;

#pragma unroll 1
    for (int half = 0; half < 4; ++half) {
        int m0h = m0 + half * 64;
        floatx4 acc[4][4] = {};                // [nt][mt]
        const short* Ap = Abf + (long)(m0h + lr) * 128 + lk;
#pragma unroll
        for (int kk = 0; kk < 4; ++kk) {
            bf16x8 afr[4];
#pragma unroll
            for (int t = 0; t < 4; ++t)
                afr[t] = *(const bf16x8*)(Ap + t * 16 * 128 + kk * 32);
#pragma unroll
            for (int nt = 0; nt < 4; ++nt)
#pragma unroll
                for (int mt = 0; mt < 4; ++mt)
                    acc[nt][mt] = __builtin_amdgcn_mfma_f32_16x16x32_bf16(
                        bfr[kk][nt], afr[mt], acc[nt][mt], 0, 0, 0);
        }

#pragma unroll
        for (int nt = 0; nt < 4; ++nt) {
#pragma unroll
            for (int mt = 0; mt < 4; ++mt) {
                int row = mt * 16 + lr;
                int col = wid * 64 + nt * 16 + colq;
                float4 o;
                o.x = acc[nt][mt][0]; o.y = acc[nt][mt][1];
                o.z = acc[nt][mt][2]; o.w = acc[nt][mt][3];
                *(float4*)&cT[row][col ^ ((row & 7) << 2)] = o;
            }
        }
        __syncthreads();
#pragma unroll
        for (int rr = 0; rr < 16; ++rr) {
            int row = wid * 16 + rr;
            float4 v = *(const float4*)&cT[row][(lane * 4) ^ ((row & 7) << 2)];
            float4 o;
            o.x = v.x + bo.x; o.y = v.y + bo.y; o.z = v.z + bo.z; o.w = v.w + bo.w;
            *(float4*)(out + (long)(m0h + row) * V_N + n0b + lane * 4) = o;
        }
        __syncthreads();
    }
}

// ---------------------------------------------------------------------------
extern "C" void kernel_launch(void* const* d_in, const int* in_sizes, int n_in,
                              void* d_out, int out_size, void* d_ws, size_t ws_size,
                              hipStream_t stream) {
    const int*   x    = (const int*)d_in[0];
    const float* emb  = (const float*)d_in[1];
    const float* Wout = (const float*)d_in[2];
    const float* bout = (const float*)d_in[3];
    const float* g1   = (const float*)d_in[4];
    const float* b1   = (const float*)d_in[5];
    const float* W1   = (const float*)d_in[6];
    const float* bfc1 = (const float*)d_in[7];
    const float* g2   = (const float*)d_in[8];
    const float* b2   = (const float*)d_in[9];
    const float* W2   = (const float*)d_in[10];
    const float* bfc2 = (const float*)d_in[11];
    float* out = (float*)d_out;

    char* ws = (char*)d_ws;
    short* WoutT    = (short*)ws;                    // 8,192,000
    short* hiddenBf = (short*)(ws + 8192000);        // 1,048,576
    float* xhatF    = (float*)(ws + 9240576);        // 2,097,152
    short* W1F      = (short*)(ws + 11337728);       // 2,752,512 (21*64 frags * 2KB)
    short* W2F      = (short*)(ws + 14090240);       // 2,752,512
    float* partials = (float*)(ws + 16842752);       // 14,680,064 (end ~31.5 MB)

    transpose_wout<<<dim3(1000, 4), dim3(256), 0, stream>>>(Wout, WoutT);
    prep_w_frag<<<dim3(16, 42), dim3(256), 0, stream>>>(W1, W2, W1F, W2F);
    ln1_prep<<<dim3(64), dim3(256), 0, stream>>>(x, emb, xhatF);
    stage1_mfma<<<dim3(1792), dim3(64), 0, stream>>>(xhatF, g1, b1,
        W1F, bfc1, g2, b2, W2F, bfc2, partials);
    finalize<<<dim3(64), dim3(256), 0, stream>>>(x, emb, partials, hiddenBf);
    stage2<<<dim3(2000), dim3(256), 0, stream>>>(hiddenBf, WoutT, bout, out);
}